// Round 5
// baseline (2121.329 us; speedup 1.0000x reference)
//
#include <hip/hip_runtime.h>

typedef __bf16 bf16;
typedef __bf16 bf16x4 __attribute__((ext_vector_type(4)));
typedef __bf16 bf16x8 __attribute__((ext_vector_type(8)));
typedef float f32x4 __attribute__((ext_vector_type(4)));
typedef unsigned int u32;
typedef unsigned short u16;

#define CL 2048
#define CN 4
#define CE 1024
#define CH 8

// ---------- async global->LDS, 16B per lane ----------
__device__ __forceinline__ void gload16(const bf16* g, bf16x8* l) {
  __builtin_amdgcn_global_load_lds((const __attribute__((address_space(1))) void*)g,
                                   (__attribute__((address_space(3))) void*)l, 16, 0, 0);
}

// ---------- 256x256 (BK=64) NT-GEMM, 8-phase counted-vmcnt schedule ----------
// 512 threads = 8 waves (2M x 4N); per-wave output 128x64 scattered as 4 64x32
// quadrants. LDS: 2 parity x 2 half x (A,B), each half 128x64 bf16 (16KB) = 128KB.
// Phase (qm,qn) Gray order (0,0),(0,1),(1,1),(1,0): reads exactly A-half qm,
// B-half qn -> halves die progressively; each phase stages ONE half-tile into
// the region that died earlier:
//   p0: (t+1).A1 -> A[d^1][1]   p1: (t+1).B0 -> B[d^1][0]
//   p2: (t+2).A0 -> A[d][0]     p3: (t+2).B1 -> B[d][1]
// At each K-tile top: vmcnt(4) (the 2 half-tiles staged after this tile's last
// half may stay in flight); vmcnt(0) only for the last K-tile. st_16x32 XOR
// swizzle (chunk ^= ((row>>2)&1)<<1) on global source + LDS read, linear dest.
__device__ __forceinline__ void gemm8p(
    const bf16* __restrict__ Abase, const bf16* __restrict__ Bbase,
    int lda, int ldb, int nk, f32x4 (&acc)[8][4])
{
  __shared__ bf16x8 Al[2][2][1024];
  __shared__ bf16x8 Bl[2][2][1024];
  const int t = threadIdx.x;
  const int lane = t & 63, w = t >> 6;
  const int wm = w >> 2, wn = w & 3;
  const int ln15 = lane & 15, kg = lane >> 4;

  // staging offsets: linear LDS index l -> row=l>>3, chunk=l&7, src chunk swizzled
  const int row0 = t >> 3;
  const int cs0 = (t & 7) ^ (((t >> 5) & 1) << 1);
  const size_t offA0 = (size_t)row0 * lda + cs0 * 8;
  const size_t offA1 = offA0 + (size_t)64 * lda;
  const size_t offB0 = (size_t)row0 * ldb + cs0 * 8;
  const size_t offB1 = offB0 + (size_t)64 * ldb;

  auto stA = [&](int d, int h, int tt) {
    const bf16* g = Abase + (size_t)h * 128 * lda + tt * 64;
    gload16(g + offA0, &Al[d][h][t]);
    gload16(g + offA1, &Al[d][h][t + 512]);
  };
  auto stB = [&](int d, int h, int tt) {
    const bf16* g = Bbase + (size_t)h * 128 * ldb + tt * 64;
    gload16(g + offB0, &Bl[d][h][t]);
    gload16(g + offB1, &Bl[d][h][t + 512]);
  };

  // fragment read indices (same for either half)
  int ixA[4][2], ixB[2][2];
#pragma unroll
  for (int i = 0; i < 4; ++i) {
    int r = wm * 64 + i * 16 + ln15;
    int sw = ((r >> 2) & 1) << 1;
#pragma unroll
    for (int kk = 0; kk < 2; ++kk) ixA[i][kk] = r * 8 + ((kk * 4 + kg) ^ sw);
  }
#pragma unroll
  for (int j = 0; j < 2; ++j) {
    int r = wn * 32 + j * 16 + ln15;
    int sw = ((r >> 2) & 1) << 1;
#pragma unroll
    for (int kk = 0; kk < 2; ++kk) ixB[j][kk] = r * 8 + ((kk * 4 + kg) ^ sw);
  }

  // prologue: t0 fully, then t1.A0, t1.B1 (t1.A1/B0 staged during t0 p0/p1)
  stA(0, 0, 0); stB(0, 0, 0); stA(0, 1, 0); stB(0, 1, 0);
  if (nk > 1) { stA(1, 0, 1); stB(1, 1, 1); }

  for (int kt = 0; kt < nk; ++kt) {
    const int d = kt & 1;
    if (kt < nk - 1) asm volatile("s_waitcnt vmcnt(4)" ::: "memory");
    else             asm volatile("s_waitcnt vmcnt(0)" ::: "memory");
    __builtin_amdgcn_s_barrier();   // K-tile kt resident for all waves
#pragma unroll
    for (int p = 0; p < 4; ++p) {
      const int qm = p >> 1, qn = (p >> 1) ^ (p & 1);
      bf16x8 av[4][2], bv[2][2];
#pragma unroll
      for (int i = 0; i < 4; ++i)
#pragma unroll
        for (int kk = 0; kk < 2; ++kk) av[i][kk] = Al[d][qm][ixA[i][kk]];
#pragma unroll
      for (int j = 0; j < 2; ++j)
#pragma unroll
        for (int kk = 0; kk < 2; ++kk) bv[j][kk] = Bl[d][qn][ixB[j][kk]];
      __builtin_amdgcn_sched_barrier(0);  // reads issued before stage
      if (p == 0)      { if (kt + 1 < nk) stA(d ^ 1, 1, kt + 1); }
      else if (p == 1) { if (kt + 1 < nk) stB(d ^ 1, 0, kt + 1); }
      else if (p == 2) { if (kt + 2 < nk) stA(d, 0, kt + 2); }
      else             { if (kt + 2 < nk) stB(d, 1, kt + 2); }
      __builtin_amdgcn_s_barrier();
      __builtin_amdgcn_s_setprio(1);
#pragma unroll
      for (int i = 0; i < 4; ++i)
#pragma unroll
        for (int j = 0; j < 2; ++j)
#pragma unroll
          for (int kk = 0; kk < 2; ++kk)
            acc[qm * 4 + i][qn * 2 + j] = __builtin_amdgcn_mfma_f32_16x16x32_bf16(
                av[i][kk], bv[j][kk], acc[qm * 4 + i][qn * 2 + j], 0, 0, 0);
      __builtin_amdgcn_s_setprio(0);
      __builtin_amdgcn_sched_barrier(0);  // pin MFMA (pure ops) above bar2
      __builtin_amdgcn_s_barrier();
    }
  }
}

// epilogue index helpers: row/col inside the 256-tile
#define EPI_ROW(mi, r) (((mi) >> 2) * 128 + wm * 64 + ((mi) & 3) * 16 + kg * 4 + (r))
#define EPI_COL(nj)    (((nj) >> 1) * 128 + wn * 32 + ((nj) & 1) * 16 + ln15)

// ---------- kernels ----------
__global__ void k_cast(const float4* __restrict__ in, bf16x4* __restrict__ out, int n4) {
  int i = blockIdx.x * 256 + threadIdx.x;
  if (i < n4) {
    float4 v = in[i];
    bf16x4 o = {(bf16)v.x, (bf16)v.y, (bf16)v.z, (bf16)v.w};
    out[i] = o;
  }
}

// QKV: z = head-in-chunk. [8192,1024] @ Wh[3072,1024]^T; q/k/v [pair][L][E],
// pair = z*4+n; Q pre-scaled 1/32. Grid (32, 12, chunk), 512 threads.
__global__ __launch_bounds__(512, 2)
void k_qkv(const bf16* __restrict__ xb, const bf16* __restrict__ Whb,
           const float* __restrict__ bqkvc,
           bf16* __restrict__ qb, bf16* __restrict__ kb, bf16* __restrict__ vb)
{
  const int bm = blockIdx.x, bn = blockIdx.y, z = blockIdx.z;
  f32x4 acc[8][4] = {};
  const bf16* Ab = xb + (size_t)bm * 256 * CE;
  const bf16* Bb = Whb + (size_t)z * 3 * CE * CE + (size_t)bn * 256 * CE;
  gemm8p(Ab, Bb, CE, CE, CE / 64, acc);

  const int lane = threadIdx.x & 63, w = threadIdx.x >> 6;
  const int wm = w >> 2, wn = w & 3, ln15 = lane & 15, kg = lane >> 4;
  const int f0 = bn * 256;
  const float* bias = bqkvc + (size_t)z * 3 * CE;
  bf16* dst; int e0; float scale = 1.0f;
  if (f0 < CE)          { dst = qb; e0 = f0;          scale = 0.03125f; }
  else if (f0 < 2 * CE) { dst = kb; e0 = f0 - CE; }
  else                  { dst = vb; e0 = f0 - 2 * CE; }
#pragma unroll
  for (int mi = 0; mi < 8; ++mi)
#pragma unroll
    for (int r = 0; r < 4; ++r) {
      int m = bm * 256 + EPI_ROW(mi, r);
      int l = m >> 2, n = m & 3;
      size_t rowbase = ((size_t)(z * 4 + n) * CL + l) * CE;
#pragma unroll
      for (int nj = 0; nj < 4; ++nj) {
        int fo = EPI_COL(nj);
        float v = acc[mi][nj][r] + bias[f0 + fo];
        dst[rowbase + e0 + fo] = (bf16)(v * scale);
      }
    }
}

// V transpose per pair: [L][E] -> [E][L]
__global__ void k_transpose(const bf16* __restrict__ v, bf16* __restrict__ vt)
{
  __shared__ u16 s[64][66];
  const bf16* src = v + (size_t)blockIdx.z * CL * CE;
  bf16* dst = vt + (size_t)blockIdx.z * CE * CL;
  const int l0 = blockIdx.x * 64, e0 = blockIdx.y * 64;
  const int t = threadIdx.x;
#pragma unroll
  for (int rr = 0; rr < 2; ++rr) {
    int c = t + rr * 256;
    int row = c >> 3, cb = (c & 7) * 8;
    uint4 d = *(const uint4*)(src + (size_t)(l0 + row) * CE + e0 + cb);
    u32* sp = (u32*)&s[row][cb];
    sp[0] = d.x; sp[1] = d.y; sp[2] = d.z; sp[3] = d.w;
  }
  __syncthreads();
  const int erow = t >> 2, lc = (t & 3) * 16;
  u32 wv[8];
#pragma unroll
  for (int q = 0; q < 8; ++q) {
    u16 a = s[lc + 2 * q][erow];
    u16 b = s[lc + 2 * q + 1][erow];
    wv[q] = (u32)a | ((u32)b << 16);
  }
  bf16* dp = dst + (size_t)(e0 + erow) * CL + l0 + lc;
  ((uint4*)dp)[0] = make_uint4(wv[0], wv[1], wv[2], wv[3]);
  ((uint4*)dp)[1] = make_uint4(wv[4], wv[5], wv[6], wv[7]);
}

// S = Q @ K^T per pair (bf16). Grid (8, 8, P), 512 threads.
__global__ __launch_bounds__(512, 2)
void k_scores(const bf16* __restrict__ qb, const bf16* __restrict__ kb,
              bf16* __restrict__ S)
{
  const int bm = blockIdx.x, bn = blockIdx.y, p = blockIdx.z;
  f32x4 acc[8][4] = {};
  const bf16* Ab = qb + (size_t)p * CL * CE + (size_t)bm * 256 * CE;
  const bf16* Bb = kb + (size_t)p * CL * CE + (size_t)bn * 256 * CE;
  gemm8p(Ab, Bb, CE, CE, CE / 64, acc);

  const int lane = threadIdx.x & 63, w = threadIdx.x >> 6;
  const int wm = w >> 2, wn = w & 3, ln15 = lane & 15, kg = lane >> 4;
  bf16* Sp = S + (size_t)p * CL * CL;
#pragma unroll
  for (int mi = 0; mi < 8; ++mi)
#pragma unroll
    for (int r = 0; r < 4; ++r) {
      int row = bm * 256 + EPI_ROW(mi, r);
#pragma unroll
      for (int nj = 0; nj < 4; ++nj) {
        int col = bn * 256 + EPI_COL(nj);
        Sp[(size_t)row * CL + col] = (bf16)acc[mi][nj][r];
      }
    }
}

// row softmax in place, one wave per row of 2048
__global__ __launch_bounds__(256)
void k_softmax(bf16* __restrict__ S)
{
  const int wid = threadIdx.x >> 6, lane = threadIdx.x & 63;
  const size_t row = (size_t)blockIdx.x * 4 + wid;
  ushort4* pv = (ushort4*)(S + row * CL);
  ushort4 d[8];
  float v[32];
#pragma unroll
  for (int c = 0; c < 8; ++c) d[c] = pv[c * 64 + lane];
#pragma unroll
  for (int c = 0; c < 8; ++c) {
    v[c*4+0] = __builtin_bit_cast(float, (u32)d[c].x << 16);
    v[c*4+1] = __builtin_bit_cast(float, (u32)d[c].y << 16);
    v[c*4+2] = __builtin_bit_cast(float, (u32)d[c].z << 16);
    v[c*4+3] = __builtin_bit_cast(float, (u32)d[c].w << 16);
  }
  float m = -1e30f;
#pragma unroll
  for (int i = 0; i < 32; ++i) m = fmaxf(m, v[i]);
#pragma unroll
  for (int o = 32; o; o >>= 1) m = fmaxf(m, __shfl_xor(m, o));
  float ssum = 0.f;
#pragma unroll
  for (int i = 0; i < 32; ++i) { v[i] = __expf(v[i] - m); ssum += v[i]; }
#pragma unroll
  for (int o = 32; o; o >>= 1) ssum += __shfl_xor(ssum, o);
  const float inv = 1.0f / ssum;
#pragma unroll
  for (int c = 0; c < 8; ++c) {
    ushort4 o;
    o.x = __builtin_bit_cast(u16, (bf16)(v[c*4+0] * inv));
    o.y = __builtin_bit_cast(u16, (bf16)(v[c*4+1] * inv));
    o.z = __builtin_bit_cast(u16, (bf16)(v[c*4+2] * inv));
    o.w = __builtin_bit_cast(u16, (bf16)(v[c*4+3] * inv));
    pv[c * 64 + lane] = o;
  }
}

// ctx = P @ V per pair; ctx [hl][m=l*4+n][e] bf16 (aliases q). Grid (8, 4, P).
__global__ __launch_bounds__(512, 2)
void k_pv(const bf16* __restrict__ S, const bf16* __restrict__ vt,
          bf16* __restrict__ ctx)
{
  const int bm = blockIdx.x, bn = blockIdx.y, p = blockIdx.z;
  f32x4 acc[8][4] = {};
  const bf16* Ab = S + (size_t)p * CL * CL + (size_t)bm * 256 * CL;
  const bf16* Bb = vt + (size_t)p * CE * CL + (size_t)bn * 256 * CL;
  gemm8p(Ab, Bb, CL, CL, CL / 64, acc);

  const int lane = threadIdx.x & 63, w = threadIdx.x >> 6;
  const int wm = w >> 2, wn = w & 3, ln15 = lane & 15, kg = lane >> 4;
  const int hl = p >> 2, n = p & 3;
  bf16* cp = ctx + (size_t)hl * (CL * CN) * CE;
#pragma unroll
  for (int mi = 0; mi < 8; ++mi)
#pragma unroll
    for (int r = 0; r < 4; ++r) {
      int l = bm * 256 + EPI_ROW(mi, r);
      int m = l * 4 + n;
#pragma unroll
      for (int nj = 0; nj < 4; ++nj) {
        int e = bn * 256 + EPI_COL(nj);
        cp[(size_t)m * CE + e] = (bf16)acc[mi][nj][r];
      }
    }
}

// out (+)= sum_{hl<chunk} ctx_hl @ Wo_hl^T + bo_hl. Grid (32, 4), 512 threads.
__global__ __launch_bounds__(512, 2)
void k_outproj(const bf16* __restrict__ ctx, const bf16* __restrict__ Wohb,
               const float* __restrict__ boc, float* __restrict__ out,
               int chunk, int init)
{
  const int bm = blockIdx.x, bn = blockIdx.y;
  f32x4 acc[8][4] = {};
  for (int hl = 0; hl < chunk; ++hl) {
    const bf16* Ab = ctx + ((size_t)hl * (CL * CN) + (size_t)bm * 256) * CE;
    const bf16* Bb = Wohb + ((size_t)hl * CE + (size_t)bn * 256) * CE;
    gemm8p(Ab, Bb, CE, CE, CE / 64, acc);
  }
  const int lane = threadIdx.x & 63, w = threadIdx.x >> 6;
  const int wm = w >> 2, wn = w & 3, ln15 = lane & 15, kg = lane >> 4;
#pragma unroll
  for (int mi = 0; mi < 8; ++mi)
#pragma unroll
    for (int r = 0; r < 4; ++r) {
      int m = bm * 256 + EPI_ROW(mi, r);
#pragma unroll
      for (int nj = 0; nj < 4; ++nj) {
        int f = bn * 256 + EPI_COL(nj);
        float bsum = 0.f;
        for (int hl = 0; hl < chunk; ++hl) bsum += boc[hl * CE + f];
        size_t idx = (size_t)m * CE + f;
        float prev = init ? 0.0f : out[idx];
        out[idx] = prev + acc[mi][nj][r] + bsum;
      }
    }
}

extern "C" void kernel_launch(void* const* d_in, const int* in_sizes, int n_in,
                              void* d_out, int out_size, void* d_ws, size_t ws_size,
                              hipStream_t stream) {
  const float* x    = (const float*)d_in[0];
  const float* Wqkv = (const float*)d_in[1];
  const float* bqkv = (const float*)d_in[2];
  const float* Wo   = (const float*)d_in[3];
  const float* bo   = (const float*)d_in[4];
  float* out = (float*)d_out;

  // choose chunk (heads per pass): 2 if ws fits (~202 MB), else 1 (~109 MB)
  const size_t Me = 1024 * 1024;
  auto need = [&](int ch) {
    return (size_t)(8 + ch * (3 + 1 + 8 + 8 + 16 + 8)) * Me * sizeof(bf16);
  };
  int chunk = (ws_size >= need(2)) ? 2 : 1;
  if (ws_size < need(1)) return;
  const int P = chunk * 4;

  bf16* xb   = (bf16*)d_ws;                            // 8 Me
  bf16* Whb  = xb   + (size_t)8 * Me;                  // chunk*3 Me
  bf16* Wohb = Whb  + (size_t)chunk * 3 * Me;          // chunk*1 Me
  bf16* qb   = Wohb + (size_t)chunk * 1 * Me;          // chunk*8 Me [ctx aliases]
  bf16* kb   = qb   + (size_t)chunk * 8 * Me;          // chunk*8 Me
  bf16* Sb   = kb   + (size_t)chunk * 8 * Me;          // chunk*16 Me [vb aliases]
  bf16* vtb  = Sb   + (size_t)chunk * 16 * Me;         // chunk*8 Me
  bf16* vb   = Sb;
  bf16* ctx  = qb;

  k_cast<<<dim3(8192), 256, 0, stream>>>((const float4*)x, (bf16x4*)xb, 8192 * 1024 / 4);

  for (int c = 0; c < CH / chunk; ++c) {
    k_cast<<<dim3(chunk * 3072), 256, 0, stream>>>(
        (const float4*)(Wqkv + (size_t)c * chunk * 3072 * 1024),
        (bf16x4*)Whb, chunk * 3072 * 1024 / 4);
    k_cast<<<dim3(chunk * 1024), 256, 0, stream>>>(
        (const float4*)(Wo + (size_t)c * chunk * 1024 * 1024),
        (bf16x4*)Wohb, chunk * 1024 * 1024 / 4);
    k_qkv<<<dim3(32, 12, chunk), 512, 0, stream>>>(
        xb, Whb, bqkv + (size_t)c * chunk * 3 * CE, qb, kb, vb);
    k_transpose<<<dim3(32, 16, P), 256, 0, stream>>>(vb, vtb);
    k_scores<<<dim3(8, 8, P), 512, 0, stream>>>(qb, kb, Sb);
    k_softmax<<<dim3(P * 512), 256, 0, stream>>>(Sb);
    k_pv<<<dim3(8, 4, P), 512, 0, stream>>>(Sb, vtb, ctx);
    k_outproj<<<dim3(32, 4), 512, 0, stream>>>(
        ctx, Wohb, bo + (size_t)c * chunk * CE, out, chunk, c == 0);
  }
}